// Round 1
// 70.662 us; speedup vs baseline: 1.0019x; 1.0019x over previous
//
#include <hip/hip_runtime.h>

// ArithmeticCompute: circle-encoded modular arithmetic over PRIMES.
// out[3][B*S][10][2] = {add, sub, mul} on the unit circle.
//
// R11: force-static restructure of R10.
//  - All per-residue loops are template fold-expressions: every table value
//    is a compile-time literal, every accumulator index is a template
//    constant. No dependence on #pragma unroll heuristics -> no runtime
//    (i*j)%P, no scratch-indexed arrays, no .rodata table loads.
//  - Blocks shrunk to 128 threads / 64 pairs -> 1024 blocks (4/CU possible
//    vs 2/CU at the old 512-block grid). __launch_bounds__(128,4) caps
//    VGPR at 128 (p29 body live-set ~70-100) -> 4 waves/SIMD target.
//  - om[] LDS buffer eliminated: mul results are written back into the ta
//    slot for that prime. Safe because subset A (offsets {0,5,6,9}) and
//    subset B (offsets {1,2,3,4,7,8}) partition the slots, and each slot
//    has exactly one phase-2 reader = its writer. LDS 33.8KB -> 11.3KB.
//  - Max pass: two shallow fmax chains over (u+w, u-w) pairs, depth H+1
//    instead of P. Fast rcp for the 1/(Sa*Sb) normalize.
//  - float4 global I/O for the bulk of phases 1/3.
//
// Wave partition (proven R5-R10): wave 0 = primes {2,13,17,29},
// wave 1 = {3,5,7,11,19,23}; ~equal ops, subset choice wave-uniform.
//
// mul per (pair, prime): quartet-folded softmax outer product (R6):
// A[k]=W[k]+W[p-k] += ua*ub, B[k]=W[k]-W[p-k] +-= va*vb;
// out_c = W0 + sum A[k]*cos_k, out_s = sum B[k]*sin_k.

#define TEMP_LOG2E 1442.6950408889634f  // softmax_temperature * log2(e)

constexpr double PI_D = 3.14159265358979323846264338327950288;

constexpr double tay_cos(double x) {
    double x2 = x * x, term = 1.0, sum = 1.0;
    for (int k = 1; k <= 15; ++k) { term *= -x2 / double((2 * k - 1) * (2 * k)); sum += term; }
    return sum;
}
constexpr double tay_sin(double x) {
    double x2 = x * x, term = x, sum = x;
    for (int k = 1; k <= 15; ++k) { term *= -x2 / double((2 * k) * (2 * k + 1)); sum += term; }
    return sum;
}
constexpr double ang_red(int r, int P) {  // 2*pi*r/P reduced to [-pi, pi]
    double x = 2.0 * PI_D * double(r) / double(P);
    return (x > PI_D) ? x - 2.0 * PI_D : x;
}

// ---- compile-time integer sequences (self-contained, shallow recursion) ----
template <int... Is> struct iseq {};
template <int N, int... Is> struct mkseq : mkseq<N - 1, N - 1, Is...> {};
template <int... Is> struct mkseq<0, Is...> { using type = iseq<Is...>; };
template <int N> using iseq_t = typename mkseq<N>::type;

// ---- per-(P,R) compile-time table scalars: guaranteed literals ----
template <int P, int R> struct CS {
    static constexpr float tc = (float)(double(TEMP_LOG2E) * tay_cos(ang_red(R, P)));
    static constexpr float ts = (float)(double(TEMP_LOG2E) * tay_sin(ang_red(R, P)));
    static constexpr float ec = (float)tay_cos(ang_red(R, P));
    static constexpr float es = (float)tay_sin(ang_red(R, P));
};

// ---- pass 1: max of scaled similarities, two shallow chains ----
template <int P, int J>
__device__ __forceinline__ void smax_step(float c, float s, float& m0, float& m1) {
    const float u = c * CS<P, J>::tc;   // even part (shared by residues J, P-J)
    const float w = s * CS<P, J>::ts;   // odd part
    m0 = fmaxf(m0, u + w);
    m1 = fmaxf(m1, u - w);
}
template <int P, int... J>
__device__ __forceinline__ float smax_impl(float c, float s, iseq<J...>) {
    float m0 = c * CS<P, 0>::tc;        // residue 0 (ts = 0)
    float m1 = -3.0e38f;
    (smax_step<P, J + 1>(c, s, m0, m1), ...);
    return fmaxf(m0, m1);
}
template <int P>
__device__ __forceinline__ float simmax(float c, float s) {
    return smax_impl<P>(c, s, iseq_t<(P - 1) / 2>{});
}

// ---- pass 2: b-side folded softmax numerators ----
template <int P, int J, int H>
__device__ __forceinline__ void b_step(float cb, float sb, float nmb, float& Sb,
                                       float (&ub)[H], float (&vb)[H]) {
    const float u = fmaf(cb, CS<P, J>::tc, nmb);
    const float w = sb * CS<P, J>::ts;
    const float e1 = __builtin_amdgcn_exp2f(u + w);
    const float e2 = __builtin_amdgcn_exp2f(u - w);
    const float uu = e1 + e2;
    Sb += uu;
    ub[J - 1] = uu;
    vb[J - 1] = e1 - e2;
}
template <int P, int H, int... J>
__device__ __forceinline__ void b_fold(float cb, float sb, float nmb, float& Sb,
                                       float (&ub)[H], float (&vb)[H], iseq<J...>) {
    (b_step<P, J + 1, H>(cb, sb, nmb, Sb, ub, vb), ...);
}

// ---- pass 3: pair loop, all indices template constants ----
template <int P, int I, int J, int H>
__device__ __forceinline__ void pair_step(float ua, float va,
                                          const float (&ub)[H], const float (&vb)[H],
                                          float (&A)[H], float (&B)[H]) {
    constexpr int K0 = (I * J) % P;     // never 0: P prime, 0 < I,J < P
    constexpr int KR = (K0 <= H) ? K0 : P - K0;
    A[KR - 1] = fmaf(ua, ub[J - 1], A[KR - 1]);
    if constexpr (K0 <= H) B[KR - 1] = fmaf(va,  vb[J - 1], B[KR - 1]);
    else                   B[KR - 1] = fmaf(-va, vb[J - 1], B[KR - 1]);
}
template <int P, int I, int H, int... J>
__device__ __forceinline__ void pair_row(float ua, float va,
                                         const float (&ub)[H], const float (&vb)[H],
                                         float (&A)[H], float (&B)[H], iseq<J...>) {
    (pair_step<P, I, J + 1, H>(ua, va, ub, vb, A, B), ...);
}
template <int P, int I, int H>
__device__ __forceinline__ void a_step(float ca, float sa, float nma, float& Sa,
                                       const float (&ub)[H], const float (&vb)[H],
                                       float (&A)[H], float (&B)[H]) {
    const float u = fmaf(ca, CS<P, I>::tc, nma);
    const float w = sa * CS<P, I>::ts;
    const float f1 = __builtin_amdgcn_exp2f(u + w);
    const float f2 = __builtin_amdgcn_exp2f(u - w);
    const float ua = f1 + f2, va = f1 - f2;
    Sa += ua;
    pair_row<P, I, H>(ua, va, ub, vb, A, B, iseq_t<H>{});
}
template <int P, int H, int... I>
__device__ __forceinline__ void a_fold(float ca, float sa, float nma, float& Sa,
                                       const float (&ub)[H], const float (&vb)[H],
                                       float (&A)[H], float (&B)[H], iseq<I...>) {
    (a_step<P, I + 1, H>(ca, sa, nma, Sa, ub, vb, A, B), ...);
}

// ---- epilogue: re-encode (cos even in k, sin odd) ----
template <int P, int K, int H>
__device__ __forceinline__ void enc_step(const float (&A)[H], const float (&B)[H],
                                         float& accC, float& accS) {
    accC = fmaf(A[K - 1], CS<P, K>::ec, accC);
    accS = fmaf(B[K - 1], CS<P, K>::es, accS);
}
template <int P, int H, int... K>
__device__ __forceinline__ void enc_fold(const float (&A)[H], const float (&B)[H],
                                         float& accC, float& accS, iseq<K...>) {
    (enc_step<P, K + 1, H>(A, B, accC, accS), ...);
}

template <int P>
__device__ __forceinline__ void mul_prime(float ca, float sa, float cb, float sb,
                                          float& oc, float& os) {
    static_assert(P % 2 == 1, "generic path requires odd P");
    constexpr int H = (P - 1) / 2;

    const float nma = -simmax<P>(ca, sa);
    const float nmb = -simmax<P>(cb, sb);

    // b-side numerators
    const float eb0 = __builtin_amdgcn_exp2f(fmaf(cb, CS<P, 0>::tc, nmb));
    float ub[H], vb[H];
    float Sb = eb0;
    b_fold<P, H>(cb, sb, nmb, Sb, ub, vb, iseq_t<H>{});

    // a-side outer loop + pair loop
    float A[H] = {}, B[H] = {};
    const float ea0 = __builtin_amdgcn_exp2f(fmaf(ca, CS<P, 0>::tc, nma));
    float Sa = ea0;
    a_fold<P, H>(ca, sa, nma, Sa, ub, vb, A, B, iseq_t<H>{});

    // Zero row/column: contributes only to W[0].
    const float W0 = ea0 * Sb + eb0 * (Sa - ea0);

    float accC = W0, accS = 0.f;
    enc_fold<P, H>(A, B, accC, accS, iseq_t<H>{});

    const float inv = __builtin_amdgcn_rcpf(Sa * Sb);
    oc = accC * inv;
    os = accS * inv;
}

// P = 2: closed form (templates (1,0), (-1,0); sin terms vanish).
template <>
__device__ __forceinline__ void mul_prime<2>(float ca, float sa, float cb, float sb,
                                             float& oc, float& os) {
    const float ka = ca * TEMP_LOG2E, kb = cb * TEMP_LOG2E;
    const float ma = fabsf(ka), mb = fabsf(kb);
    const float ea0 = __builtin_amdgcn_exp2f(ka - ma);
    const float ea1 = __builtin_amdgcn_exp2f(-ka - ma);
    const float eb0 = __builtin_amdgcn_exp2f(kb - mb);
    const float eb1 = __builtin_amdgcn_exp2f(-kb - mb);
    const float Sa = ea0 + ea1, Sb = eb0 + eb1;
    const float W0 = ea0 * Sb + eb0 * Sa - ea0 * eb0;
    const float W1 = ea1 * eb1;
    const float inv = __builtin_amdgcn_rcpf(Sa * Sb);
    oc = (W0 - W1) * inv;
    os = 0.f;
}

__global__ __launch_bounds__(128, 4) void arith_kernel(const float* __restrict__ a,
                                                       const float* __restrict__ b,
                                                       float* __restrict__ out,
                                                       int n_pairs) {
    // 64 pairs x 11 float2 slots (10 primes + pad). 11.3 KB total.
    __shared__ float2 ta[64 * 11], tb[64 * 11];

    const int t = threadIdx.x;                 // 0..127
    const int gb2 = blockIdx.x * 640;          // block base in float2
    const int gb4 = blockIdx.x * 320;          // block base in float4
    const int planef2 = n_pairs * 10;          // plane size in float2
    const int planef4 = planef2 >> 1;
    float2* o2 = (float2*)out;
    float4* o4 = (float4*)out;
    const float4* a4 = (const float4*)a;
    const float4* b4 = (const float4*)b;

    // Phase 1: coalesced load + stage + add/sub stores.
    // float4 part: float2 slots 0..511 (float4 k=0..255; 10 even -> a float4
    // never crosses a pair boundary).
#pragma unroll
    for (int it = 0; it < 2; ++it) {
        const int k = it * 128 + t;            // float4 index 0..255
        const int pr = k / 5, j = k - pr * 5;  // pair, float4-within-pair
        const int sl = pr * 11 + 2 * j;
        const float4 av = a4[gb4 + k];
        const float4 bv = b4[gb4 + k];
        ta[sl]     = make_float2(av.x, av.y);
        ta[sl + 1] = make_float2(av.z, av.w);
        tb[sl]     = make_float2(bv.x, bv.y);
        tb[sl + 1] = make_float2(bv.z, bv.w);
        float4 addv, subv;
        addv.x = av.x * bv.x - av.y * bv.y;  addv.y = av.y * bv.x + av.x * bv.y;
        addv.z = av.z * bv.z - av.w * bv.w;  addv.w = av.w * bv.z + av.z * bv.w;
        subv.x = av.x * bv.x + av.y * bv.y;  subv.y = av.y * bv.x - av.x * bv.y;
        subv.z = av.z * bv.z + av.w * bv.w;  subv.w = av.w * bv.z - av.z * bv.w;
        o4[gb4 + k]           = addv;          // add plane
        o4[planef4 + gb4 + k] = subv;          // sub plane
    }
    {   // float2 remainder: slots 512..639
        const int f2 = 512 + t;
        const int pr = f2 / 10, of = f2 - pr * 10;
        const int sl = pr * 11 + of;
        const float2 av = ((const float2*)a)[gb2 + f2];
        const float2 bv = ((const float2*)b)[gb2 + f2];
        ta[sl] = av;
        tb[sl] = bv;
        const float pcc = av.x * bv.x, pss = av.y * bv.y;
        const float psc = av.y * bv.x, pcs = av.x * bv.y;
        o2[gb2 + f2]            = make_float2(pcc - pss, psc + pcs);
        o2[planef2 + gb2 + f2]  = make_float2(pcc + pss, psc - pcs);
    }
    __syncthreads();

    // Phase 2: wave 0 (t<64) = subset A, wave 1 = subset B. Results written
    // back into the ta slot (subsets partition offsets; slot's only phase-2
    // reader is its writer).
    {
        const int rb = (t & 63) * 11;

#define DO_PRIME(P, OFI)                                                     \
        {                                                                    \
            const float2 av = ta[rb + (OFI)];                                \
            const float2 bv = tb[rb + (OFI)];                                \
            float oc, os;                                                    \
            mul_prime<P>(av.x, av.y, bv.x, bv.y, oc, os);                    \
            ta[rb + (OFI)] = make_float2(oc, os);                            \
        }

        if (t < 64) {
            // Subset A: {2, 13, 17, 29}
            DO_PRIME(29, 9)
            DO_PRIME(17, 6)
            DO_PRIME(13, 5)
            DO_PRIME(2, 0)
        } else {
            // Subset B: {3, 5, 7, 11, 19, 23}
            DO_PRIME(23, 8)
            DO_PRIME(19, 7)
            DO_PRIME(11, 4)
            DO_PRIME(7, 3)
            DO_PRIME(5, 2)
            DO_PRIME(3, 1)
        }
#undef DO_PRIME
    }
    __syncthreads();

    // Phase 3: coalesced LDS -> global for the mul plane.
#pragma unroll
    for (int it = 0; it < 2; ++it) {
        const int k = it * 128 + t;
        const int pr = k / 5, j = k - pr * 5;
        const int sl = pr * 11 + 2 * j;
        const float2 r0 = ta[sl], r1 = ta[sl + 1];
        o4[2 * planef4 + gb4 + k] = make_float4(r0.x, r0.y, r1.x, r1.y);
    }
    {
        const int f2 = 512 + t;
        const int pr = f2 / 10, of = f2 - pr * 10;
        o2[2 * planef2 + gb2 + f2] = ta[pr * 11 + of];
    }
}

extern "C" void kernel_launch(void* const* d_in, const int* in_sizes, int n_in,
                              void* d_out, int out_size, void* d_ws, size_t ws_size,
                              hipStream_t stream) {
    const float* a = (const float*)d_in[0];
    const float* b = (const float*)d_in[1];
    float* out = (float*)d_out;
    const int n_pairs = in_sizes[0] / 20;   // B*S = 65536 (multiple of 64)
    const int n_blocks = n_pairs / 64;      // 1024 blocks of 128 threads

    dim3 block(128);
    dim3 grid(n_blocks);
    arith_kernel<<<grid, block, 0, stream>>>(a, b, out, n_pairs);
}

// Round 3
// 69.907 us; speedup vs baseline: 1.0127x; 1.0108x over previous
//
#include <hip/hip_runtime.h>

// ArithmeticCompute: circle-encoded modular arithmetic over PRIMES.
// out[3][B*S][10][2] = {add, sub, mul} on the unit circle.
//
// R13 = R12 resubmitted verbatim (R12's bench was an infra failure:
// "MI355X container failed twice" -- no kernel signal). Theory unchanged:
//
// R12: packed-f32 (v_pk_fma_f32) restructure of R11. Theory: the kernel is
// front-end (I-fetch) bound -- ~28KB of straight-line unrolled code, zero
// temporal reuse, ~25cy/inst fetch stall -- which explains why R10->R11
// (geometry/static-index restructure) was a 0.2% no-op. Packing halves both
// dynamic VALU issue AND static code bytes for the dominant sections:
//  - pair loop: (A[k],B[k]) += (ua,+-va)*(ub[j],vb[j]) as ONE pk_fma
//    (sign folded into compile-time pick of (ua,va) vs (ua,-va));
//    1074 -> 537 insts, all-register operands.
//  - smax pass: residues (J, P-J) share even/odd parts: sims for both
//    computed as 2 pk ops + 1 pk_max vs 4 scalar + 2 fmax.
//  - softmax numerator passes: same (J, P-J) pairing, 2 pk ops per step.
// Geometry unchanged from R11 (128 thr / 64 pairs / 1024 blocks; add/sub
// inline in phase 1; mul result written back into ta slots).
//
// Wave partition (proven R5-R11): wave 0 = primes {2,13,17,29},
// wave 1 = {3,5,7,11,19,23}; ~equal ops, subset choice wave-uniform.

#define TEMP_LOG2E 1442.6950408889634f  // softmax_temperature * log2(e)

typedef float v2 __attribute__((ext_vector_type(2)));

constexpr double PI_D = 3.14159265358979323846264338327950288;

constexpr double tay_cos(double x) {
    double x2 = x * x, term = 1.0, sum = 1.0;
    for (int k = 1; k <= 15; ++k) { term *= -x2 / double((2 * k - 1) * (2 * k)); sum += term; }
    return sum;
}
constexpr double tay_sin(double x) {
    double x2 = x * x, term = x, sum = x;
    for (int k = 1; k <= 15; ++k) { term *= -x2 / double((2 * k) * (2 * k + 1)); sum += term; }
    return sum;
}
constexpr double ang_red(int r, int P) {  // 2*pi*r/P reduced to [-pi, pi]
    double x = 2.0 * PI_D * double(r) / double(P);
    return (x > PI_D) ? x - 2.0 * PI_D : x;
}

// ---- compile-time integer sequences ----
template <int... Is> struct iseq {};
template <int N, int... Is> struct mkseq : mkseq<N - 1, N - 1, Is...> {};
template <int... Is> struct mkseq<0, Is...> { using type = iseq<Is...>; };
template <int N> using iseq_t = typename mkseq<N>::type;

// ---- per-(P,R) compile-time table scalars: guaranteed literals ----
template <int P, int R> struct CS {
    static constexpr float tc = (float)(double(TEMP_LOG2E) * tay_cos(ang_red(R, P)));
    static constexpr float ts = (float)(double(TEMP_LOG2E) * tay_sin(ang_red(R, P)));
    static constexpr float ec = (float)tay_cos(ang_red(R, P));
    static constexpr float es = (float)tay_sin(ang_red(R, P));
};

// Packed similarity for the residue pair (J, P-J):
//   sim_J   = c*tc + s*ts   (lane .x)
//   sim_P-J = c*tc - s*ts   (lane .y)
template <int P, int J>
__device__ __forceinline__ v2 sim2(v2 c2, v2 s2, v2 nm2) {
    const v2 tc2 = {CS<P, J>::tc, CS<P, J>::tc};
    const v2 ts2 = {CS<P, J>::ts, -CS<P, J>::ts};
    return s2 * ts2 + (c2 * tc2 + nm2);   // 2x pk_fma
}

// ---- pass 1: max of scaled similarities (packed pair chains) ----
template <int P, int J>
__device__ __forceinline__ void smax_step(v2 c2, v2 s2, v2& m2) {
    const v2 tc2 = {CS<P, J>::tc, CS<P, J>::tc};
    const v2 ts2 = {CS<P, J>::ts, -CS<P, J>::ts};
    m2 = __builtin_elementwise_max(m2, s2 * ts2 + c2 * tc2);
}
template <int P, int... J>
__device__ __forceinline__ float smax_impl(float c, float s, iseq<J...>) {
    const v2 c2 = {c, c}, s2 = {s, s};
    v2 m2 = {c * CS<P, 0>::tc, -3.0e38f};   // residue 0 (ts = 0)
    (smax_step<P, J + 1>(c2, s2, m2), ...);
    return fmaxf(m2.x, m2.y);
}
template <int P>
__device__ __forceinline__ float simmax(float c, float s) {
    return smax_impl<P>(c, s, iseq_t<(P - 1) / 2>{});
}

// ---- pass 2: b-side folded softmax numerators, packed (ub,vb) ----
template <int P, int J, int H>
__device__ __forceinline__ void b_step(v2 cb2, v2 sb2, v2 nmb2, float& Sb,
                                       v2 (&uvb)[H]) {
    const v2 u2 = sim2<P, J>(cb2, sb2, nmb2);
    const float e1 = __builtin_amdgcn_exp2f(u2.x);
    const float e2 = __builtin_amdgcn_exp2f(u2.y);
    uvb[J - 1] = (v2){e1 + e2, e1 - e2};
    Sb += e1 + e2;
}
template <int P, int H, int... J>
__device__ __forceinline__ void b_fold(v2 cb2, v2 sb2, v2 nmb2, float& Sb,
                                       v2 (&uvb)[H], iseq<J...>) {
    (b_step<P, J + 1, H>(cb2, sb2, nmb2, Sb, uvb), ...);
}

// ---- pass 3: pair loop, one pk_fma per (I,J), indices template constants ----
template <int P, int I, int J, int H>
__device__ __forceinline__ void pair_step(v2 uva_p, v2 uva_m,
                                          const v2 (&uvb)[H], v2 (&acc)[H]) {
    constexpr int K0 = (I * J) % P;     // never 0: P prime, 0 < I,J < P
    constexpr int KR = (K0 <= H) ? K0 : P - K0;
    if constexpr (K0 <= H) acc[KR - 1] = uva_p * uvb[J - 1] + acc[KR - 1];
    else                   acc[KR - 1] = uva_m * uvb[J - 1] + acc[KR - 1];
}
template <int P, int I, int H, int... J>
__device__ __forceinline__ void pair_row(v2 uva_p, v2 uva_m,
                                         const v2 (&uvb)[H], v2 (&acc)[H],
                                         iseq<J...>) {
    (pair_step<P, I, J + 1, H>(uva_p, uva_m, uvb, acc), ...);
}
template <int P, int I, int H>
__device__ __forceinline__ void a_step(v2 ca2, v2 sa2, v2 nma2, float& Sa,
                                       const v2 (&uvb)[H], v2 (&acc)[H]) {
    const v2 u2 = sim2<P, I>(ca2, sa2, nma2);
    const float f1 = __builtin_amdgcn_exp2f(u2.x);
    const float f2 = __builtin_amdgcn_exp2f(u2.y);
    const float ua = f1 + f2, va = f1 - f2;
    Sa += ua;
    const v2 uva_p = {ua, va};
    const v2 uva_m = {ua, -va};
    pair_row<P, I, H>(uva_p, uva_m, uvb, acc, iseq_t<H>{});
}
template <int P, int H, int... I>
__device__ __forceinline__ void a_fold(v2 ca2, v2 sa2, v2 nma2, float& Sa,
                                       const v2 (&uvb)[H], v2 (&acc)[H],
                                       iseq<I...>) {
    (a_step<P, I + 1, H>(ca2, sa2, nma2, Sa, uvb, acc), ...);
}

// ---- epilogue: re-encode (cos even in k, sin odd); scalar (2 literals
// per step can't share one VOP3P literal slot) ----
template <int P, int K, int H>
__device__ __forceinline__ void enc_step(const v2 (&acc)[H], float& accC, float& accS) {
    accC = fmaf(acc[K - 1].x, CS<P, K>::ec, accC);
    accS = fmaf(acc[K - 1].y, CS<P, K>::es, accS);
}
template <int P, int H, int... K>
__device__ __forceinline__ void enc_fold(const v2 (&acc)[H], float& accC, float& accS,
                                         iseq<K...>) {
    (enc_step<P, K + 1, H>(acc, accC, accS), ...);
}

template <int P>
__device__ __forceinline__ void mul_prime(float ca, float sa, float cb, float sb,
                                          float& oc, float& os) {
    static_assert(P % 2 == 1, "generic path requires odd P");
    constexpr int H = (P - 1) / 2;

    const float nma = -simmax<P>(ca, sa);
    const float nmb = -simmax<P>(cb, sb);

    const v2 ca2 = {ca, ca}, sa2 = {sa, sa}, nma2 = {nma, nma};
    const v2 cb2 = {cb, cb}, sb2 = {sb, sb}, nmb2 = {nmb, nmb};

    // b-side numerators (packed (ub, vb) per residue pair)
    const float eb0 = __builtin_amdgcn_exp2f(fmaf(cb, CS<P, 0>::tc, nmb));
    v2 uvb[H];
    float Sb = eb0;
    b_fold<P, H>(cb2, sb2, nmb2, Sb, uvb, iseq_t<H>{});

    // a-side outer loop + packed pair loop
    v2 acc[H] = {};
    const float ea0 = __builtin_amdgcn_exp2f(fmaf(ca, CS<P, 0>::tc, nma));
    float Sa = ea0;
    a_fold<P, H>(ca2, sa2, nma2, Sa, uvb, acc, iseq_t<H>{});

    // Zero row/column: contributes only to W[0].
    const float W0 = ea0 * Sb + eb0 * (Sa - ea0);

    float accC = W0, accS = 0.f;
    enc_fold<P, H>(acc, accC, accS, iseq_t<H>{});

    const float inv = __builtin_amdgcn_rcpf(Sa * Sb);
    oc = accC * inv;
    os = accS * inv;
}

// P = 2: closed form (templates (1,0), (-1,0); sin terms vanish).
template <>
__device__ __forceinline__ void mul_prime<2>(float ca, float sa, float cb, float sb,
                                             float& oc, float& os) {
    const float ka = ca * TEMP_LOG2E, kb = cb * TEMP_LOG2E;
    const float ma = fabsf(ka), mb = fabsf(kb);
    const float ea0 = __builtin_amdgcn_exp2f(ka - ma);
    const float ea1 = __builtin_amdgcn_exp2f(-ka - ma);
    const float eb0 = __builtin_amdgcn_exp2f(kb - mb);
    const float eb1 = __builtin_amdgcn_exp2f(-kb - mb);
    const float Sa = ea0 + ea1, Sb = eb0 + eb1;
    const float W0 = ea0 * Sb + eb0 * Sa - ea0 * eb0;
    const float W1 = ea1 * eb1;
    const float inv = __builtin_amdgcn_rcpf(Sa * Sb);
    oc = (W0 - W1) * inv;
    os = 0.f;
}

__global__ __launch_bounds__(128, 4) void arith_kernel(const float* __restrict__ a,
                                                       const float* __restrict__ b,
                                                       float* __restrict__ out,
                                                       int n_pairs) {
    // 64 pairs x 11 float2 slots (10 primes + pad). 11.3 KB total.
    __shared__ float2 ta[64 * 11], tb[64 * 11];

    const int t = threadIdx.x;                 // 0..127
    const int gb2 = blockIdx.x * 640;          // block base in float2
    const int gb4 = blockIdx.x * 320;          // block base in float4
    const int planef2 = n_pairs * 10;          // plane size in float2
    const int planef4 = planef2 >> 1;
    float2* o2 = (float2*)out;
    float4* o4 = (float4*)out;
    const float4* a4 = (const float4*)a;
    const float4* b4 = (const float4*)b;

    // Phase 1: coalesced load + stage + add/sub stores.
#pragma unroll
    for (int it = 0; it < 2; ++it) {
        const int k = it * 128 + t;            // float4 index 0..255
        const int pr = k / 5, j = k - pr * 5;  // pair, float4-within-pair
        const int sl = pr * 11 + 2 * j;
        const float4 av = a4[gb4 + k];
        const float4 bv = b4[gb4 + k];
        ta[sl]     = make_float2(av.x, av.y);
        ta[sl + 1] = make_float2(av.z, av.w);
        tb[sl]     = make_float2(bv.x, bv.y);
        tb[sl + 1] = make_float2(bv.z, bv.w);
        float4 addv, subv;
        addv.x = av.x * bv.x - av.y * bv.y;  addv.y = av.y * bv.x + av.x * bv.y;
        addv.z = av.z * bv.z - av.w * bv.w;  addv.w = av.w * bv.z + av.z * bv.w;
        subv.x = av.x * bv.x + av.y * bv.y;  subv.y = av.y * bv.x - av.x * bv.y;
        subv.z = av.z * bv.z + av.w * bv.w;  subv.w = av.w * bv.z - av.z * bv.w;
        o4[gb4 + k]           = addv;          // add plane
        o4[planef4 + gb4 + k] = subv;          // sub plane
    }
    {   // float2 remainder: slots 512..639
        const int f2 = 512 + t;
        const int pr = f2 / 10, of = f2 - pr * 10;
        const int sl = pr * 11 + of;
        const float2 av = ((const float2*)a)[gb2 + f2];
        const float2 bv = ((const float2*)b)[gb2 + f2];
        ta[sl] = av;
        tb[sl] = bv;
        const float pcc = av.x * bv.x, pss = av.y * bv.y;
        const float psc = av.y * bv.x, pcs = av.x * bv.y;
        o2[gb2 + f2]            = make_float2(pcc - pss, psc + pcs);
        o2[planef2 + gb2 + f2]  = make_float2(pcc + pss, psc - pcs);
    }
    __syncthreads();

    // Phase 2: wave 0 (t<64) = subset A, wave 1 = subset B. Results written
    // back into the ta slot (subsets partition offsets; slot's only phase-2
    // reader is its writer).
    {
        const int rb = (t & 63) * 11;

#define DO_PRIME(P, OFI)                                                     \
        {                                                                    \
            const float2 av = ta[rb + (OFI)];                                \
            const float2 bv = tb[rb + (OFI)];                                \
            float oc, os;                                                    \
            mul_prime<P>(av.x, av.y, bv.x, bv.y, oc, os);                    \
            ta[rb + (OFI)] = make_float2(oc, os);                            \
        }

        if (t < 64) {
            // Subset A: {2, 13, 17, 29}
            DO_PRIME(29, 9)
            DO_PRIME(17, 6)
            DO_PRIME(13, 5)
            DO_PRIME(2, 0)
        } else {
            // Subset B: {3, 5, 7, 11, 19, 23}
            DO_PRIME(23, 8)
            DO_PRIME(19, 7)
            DO_PRIME(11, 4)
            DO_PRIME(7, 3)
            DO_PRIME(5, 2)
            DO_PRIME(3, 1)
        }
#undef DO_PRIME
    }
    __syncthreads();

    // Phase 3: coalesced LDS -> global for the mul plane.
#pragma unroll
    for (int it = 0; it < 2; ++it) {
        const int k = it * 128 + t;
        const int pr = k / 5, j = k - pr * 5;
        const int sl = pr * 11 + 2 * j;
        const float2 r0 = ta[sl], r1 = ta[sl + 1];
        o4[2 * planef4 + gb4 + k] = make_float4(r0.x, r0.y, r1.x, r1.y);
    }
    {
        const int f2 = 512 + t;
        const int pr = f2 / 10, of = f2 - pr * 10;
        o2[2 * planef2 + gb2 + f2] = ta[pr * 11 + of];
    }
}

extern "C" void kernel_launch(void* const* d_in, const int* in_sizes, int n_in,
                              void* d_out, int out_size, void* d_ws, size_t ws_size,
                              hipStream_t stream) {
    const float* a = (const float*)d_in[0];
    const float* b = (const float*)d_in[1];
    float* out = (float*)d_out;
    const int n_pairs = in_sizes[0] / 20;   // B*S = 65536 (multiple of 64)
    const int n_blocks = n_pairs / 64;      // 1024 blocks of 256 threads

    dim3 block(128);
    dim3 grid(n_blocks);
    arith_kernel<<<grid, block, 0, stream>>>(a, b, out, n_pairs);
}